// Round 8
// baseline (4071.814 us; speedup 1.0000x reference)
//
#include <hip/hip_runtime.h>
#include <stdint.h>

#define BB 8
#define CCH 64
#define NPB 4096
#define KK 16
#define NPTS (BB*NPB)   // 32768
#define SPLITS 8

typedef float vf16 __attribute__((ext_vector_type(16)));
typedef unsigned long long u64;

// ---------------- K1: transpose x (B,C,N) -> xb (B,N,C) ----------------
__global__ void k_transpose(const float* __restrict__ x, float* __restrict__ xb) {
    __shared__ float tile[64][65];
    int b  = blockIdx.y;
    int n0 = blockIdx.x * 64;
    int tx = threadIdx.x, ty = threadIdx.y;   // 64 x 8
    const float* xp = x + (size_t)b * CCH * NPB;
#pragma unroll
    for (int r = 0; r < 8; ++r) {
        int c = ty + r * 8;
        tile[c][tx] = xp[(size_t)c * NPB + n0 + tx];
    }
    __syncthreads();
    float* xbp = xb + ((size_t)b * NPB + n0) * CCH;
#pragma unroll
    for (int r = 0; r < 8; ++r) {
        int nn = ty + r * 8;
        xbp[(size_t)nn * CCH + tx] = tile[tx][nn];
    }
}

// ---------------- K1b: per-point sum of squares ----------------
__global__ void k_sq(const float* __restrict__ xb, float* __restrict__ sq) {
    int p = blockIdx.x * 256 + threadIdx.x;
    const float4* r = (const float4*)(xb + (size_t)p * CCH);
    float s = 0.0f;
#pragma unroll
    for (int i = 0; i < 16; ++i) {
        float4 v = r[i];
        s += v.x * v.x + v.y * v.y + v.z * v.z + v.w * v.w;
    }
    sq[p] = s;
}

// ---------------- K2: distances + per-(row,colsplit) top-16 ----------------
// R6 geometry (512 threads, grid (8,64)) + bitonic selection verbatim.
// Distance accumulation restructured: 4 cols/group x (lo,hi) feature halves
// = 8 independent FMA chains (issue-bound, not dep-bound); group's 16 vf16
// loads issue as a batch and hide under previous group's FMAs / sort.
// __launch_bounds__(512,1): VGPR cap 256 (empirical cap = 512/(2*minwaves)).
// key = (monotonic_bits(d) << 32) | col -> lex (d asc, idx asc)
__global__ __launch_bounds__(512, 1) void k_knn(const float* __restrict__ xb,
                                                const float* __restrict__ sq,
                                                u64* __restrict__ cand) {
    int tid  = threadIdx.x;
    int row  = blockIdx.y * 512 + tid;          // global point (per-lane)
    int b    = row >> 12;                       // per-lane on purpose
    int split = blockIdx.x;
    const float* xbB = xb + ((size_t)(b) << 12) * CCH;
    const float* sqB = sq + ((size_t)(b) << 12);

    // my row's features -> registers
    float rr[CCH];
    {
        const float4* rp = (const float4*)(xbB + (size_t)(row & 4095) * CCH);
#pragma unroll
        for (int i = 0; i < 16; ++i) {
            float4 v = rp[i];
            rr[4*i] = v.x; rr[4*i+1] = v.y; rr[4*i+2] = v.z; rr[4*i+3] = v.w;
        }
    }

    u64 list[16];
#pragma unroll
    for (int s = 0; s < 16; ++s) list[s] = ~0ULL;

    int colBase = split * (NPB / SPLITS);       // 512 cols per split
    for (int t = 0; t < (NPB / SPLITS) / 16; ++t) {   // 32 subtiles of 16 cols
        int c0 = colBase + t * 16;
        u64 key[16];
#pragma unroll
        for (int g = 0; g < 4; ++g) {           // 4 groups of 4 cols
            int cg = c0 + g * 4;
            vf16 v[4][4];
#pragma unroll
            for (int c = 0; c < 4; ++c) {
                const float* cp_ = xbB + (size_t)(cg + c) * CCH;
#pragma unroll
                for (int q = 0; q < 4; ++q)
                    v[c][q] = *(const vf16*)(cp_ + q * 16);
            }
#pragma unroll
            for (int c = 0; c < 4; ++c) {
                float lo = 0.f, hi = 0.f;       // 2 chains per col, 8 per group
#pragma unroll
                for (int q = 0; q < 2; ++q) {
#pragma unroll
                    for (int e = 0; e < 16; ++e) {
                        lo = fmaf(v[c][q][e],     rr[q * 16 + e],      lo);
                        hi = fmaf(v[c][q + 2][e], rr[32 + q * 16 + e], hi);
                    }
                }
                float dd = fmaf(-2.f, lo + hi, sqB[cg + c]);
                unsigned int fb = __float_as_uint(dd);
                fb ^= (fb >> 31) ? 0xFFFFFFFFu : 0x80000000u;   // monotonic
                key[g * 4 + c] = ((u64)fb << 32) | (unsigned int)(cg + c);
            }
        }
        // ---- bitonic sort16 ascending (static indices, branchless) ----
#pragma unroll
        for (int kk = 2; kk <= 16; kk <<= 1) {
#pragma unroll
            for (int j = kk >> 1; j > 0; j >>= 1) {
#pragma unroll
                for (int i = 0; i < 16; ++i) {
                    int l = i ^ j;
                    if (l > i) {
                        bool up = ((i & kk) == 0);
                        u64 a = key[i], c = key[l];
                        bool cond = up ? (c < a) : (a < c);
                        key[i] = cond ? c : a;
                        key[l] = cond ? a : c;
                    }
                }
            }
        }
        // ---- merge: keep 16 smallest of (list[16] asc, key[16] asc) ----
        u64 m[16];
#pragma unroll
        for (int i = 0; i < 16; ++i) {
            u64 a = list[i], c = key[15 - i];
            m[i] = (c < a) ? c : a;            // bitonic result
        }
#pragma unroll
        for (int j = 8; j > 0; j >>= 1) {
#pragma unroll
            for (int i = 0; i < 16; ++i) {
                if ((i & j) == 0) {
                    u64 a = m[i], c = m[i + j];
                    bool cond = c < a;
                    m[i]     = cond ? c : a;
                    m[i + j] = cond ? a : c;
                }
            }
        }
#pragma unroll
        for (int i = 0; i < 16; ++i) list[i] = m[i];
    }
    u64* cp = cand + (((size_t)row * SPLITS) + split) * 16;
#pragma unroll
    for (int s = 0; s < 16; ++s) cp[s] = list[s];
}

// ---------------- K3: merge SPLITS sorted 16-lists -> final idx[16] ----------------
__global__ void k_merge(const u64* __restrict__ cand,
                        int* __restrict__ idxo) {
    int row = blockIdx.x * 256 + threadIdx.x;
    const u64* cp = cand + (size_t)row * (SPLITS * 16);
    int p[SPLITS];
#pragma unroll
    for (int s = 0; s < SPLITS; ++s) p[s] = 0;
    for (int k = 0; k < 16; ++k) {
        u64 m = ~0ULL; int w = 0;
#pragma unroll
        for (int s = 0; s < SPLITS; ++s) {
            u64 v = cp[s * 16 + p[s]];
            if (v < m) { m = v; w = s; }       // strict: earlier split wins ties
        }
#pragma unroll
        for (int s = 0; s < SPLITS; ++s) p[s] += (s == w) ? 1 : 0;
        idxo[(size_t)row * 16 + k] = (int)(m & 0xFFFFFFFFu);
    }
}

// ---------------- K4: fused edge-MLP + max over K (proven body) ----------------
__global__ __launch_bounds__(256, 2) void k_mlp(const float* __restrict__ xb,
                                                const int* __restrict__ idx,
                                                const float* __restrict__ W1,
                                                const float* __restrict__ b1,
                                                const float* __restrict__ W2,
                                                const float* __restrict__ b2,
                                                float* __restrict__ out) {
    int lane = threadIdx.x & 63;
    int wave = (blockIdx.x * 256 + threadIdx.x) >> 6;   // 0..2047
    int o = lane;
    float wa[64], wb[64], w2r[64];
#pragma unroll
    for (int c = 0; c < 64; ++c) {
        float w1a = W1[c * 64 + o];
        float w1b = W1[(64 + c) * 64 + o];
        wa[c] = w1a - w1b;
        wb[c] = w1b;
        w2r[c] = W2[c * 64 + o];
    }
    float bb1 = b1[o], bb2 = b2[o];
    int p0 = wave * 16;
    for (int pi = 0; pi < 16; ++pi) {
        int p = p0 + pi;
        int b = p >> 12;
        int n = p & 4095;
        const float* xbB = xb + ((size_t)b << 12) * CCH;
        const float* xi = xbB + (size_t)n * CCH;
        float pre = bb1;
#pragma unroll
        for (int c4 = 0; c4 < 16; ++c4) {
            float4 v = *(const float4*)(xi + c4 * 4);
            pre = fmaf(v.x, wa[c4 * 4 + 0], pre);
            pre = fmaf(v.y, wa[c4 * 4 + 1], pre);
            pre = fmaf(v.z, wa[c4 * 4 + 2], pre);
            pre = fmaf(v.w, wa[c4 * 4 + 3], pre);
        }
        const int* ip = idx + (size_t)p * 16;
        float mx = 0.f;
        for (int k = 0; k < 16; ++k) {
            int j = ip[k];
            const float* xj = xbB + (size_t)j * CCH;
            float h = pre;
#pragma unroll
            for (int c4 = 0; c4 < 16; ++c4) {
                float4 v = *(const float4*)(xj + c4 * 4);
                h = fmaf(v.x, wb[c4 * 4 + 0], h);
                h = fmaf(v.y, wb[c4 * 4 + 1], h);
                h = fmaf(v.z, wb[c4 * 4 + 2], h);
                h = fmaf(v.w, wb[c4 * 4 + 3], h);
            }
            float h1 = fmaxf(h, 0.f);
            float a0 = bb2, a1 = 0.f, a2 = 0.f, a3 = 0.f;
#pragma unroll
            for (int j4 = 0; j4 < 16; ++j4) {
                float h0  = __int_as_float(__builtin_amdgcn_readlane(__float_as_int(h1), 4*j4+0));
                float hh1 = __int_as_float(__builtin_amdgcn_readlane(__float_as_int(h1), 4*j4+1));
                float h2  = __int_as_float(__builtin_amdgcn_readlane(__float_as_int(h1), 4*j4+2));
                float h3  = __int_as_float(__builtin_amdgcn_readlane(__float_as_int(h1), 4*j4+3));
                a0 = fmaf(h0,  w2r[4*j4+0], a0);
                a1 = fmaf(hh1, w2r[4*j4+1], a1);
                a2 = fmaf(h2,  w2r[4*j4+2], a2);
                a3 = fmaf(h3,  w2r[4*j4+3], a3);
            }
            float acc = (a0 + a1) + (a2 + a3);
            float h2o = fmaxf(acc, 0.f);
            mx = fmaxf(mx, h2o);
        }
        out[((size_t)b * 64 + o) * NPB + n] = mx;
    }
}

extern "C" void kernel_launch(void* const* d_in, const int* in_sizes, int n_in,
                              void* d_out, int out_size, void* d_ws, size_t ws_size,
                              hipStream_t stream) {
    const float* x  = (const float*)d_in[0];
    const float* W1 = (const float*)d_in[1];
    const float* b1 = (const float*)d_in[2];
    const float* W2 = (const float*)d_in[3];
    const float* b2 = (const float*)d_in[4];
    float* out = (float*)d_out;

    char* ws = (char*)d_ws;
    float* xb = (float*)ws;                                       // 8 MB
    float* sq = (float*)(ws + (size_t)8 * 1024 * 1024);           // 128 KB
    u64* cand = (u64*)(ws + (size_t)9 * 1024 * 1024);             // 32 MB
    int* idxb = (int*)(ws + (size_t)9 * 1024 * 1024
                          + (size_t)NPTS * SPLITS * 16 * 8);      // 2 MB

    hipLaunchKernelGGL(k_transpose, dim3(NPB / 64, BB), dim3(64, 8), 0, stream, x, xb);
    hipLaunchKernelGGL(k_sq, dim3(NPTS / 256), dim3(256), 0, stream, xb, sq);
    hipLaunchKernelGGL(k_knn, dim3(SPLITS, NPTS / 512), dim3(512), 0, stream, xb, sq, cand);
    hipLaunchKernelGGL(k_merge, dim3(NPTS / 256), dim3(256), 0, stream, cand, idxb);
    hipLaunchKernelGGL(k_mlp, dim3(512), dim3(256), 0, stream, xb, idxb, W1, b1, W2, b2, out);
}

// Round 9
// 1486.591 us; speedup vs baseline: 2.7390x; 2.7390x over previous
//
#include <hip/hip_runtime.h>
#include <stdint.h>

#define BB 8
#define CCH 64
#define NPB 4096
#define KK 16
#define NPTS (BB*NPB)   // 32768
#define SPLITS 8

typedef float vf16 __attribute__((ext_vector_type(16)));
typedef unsigned long long u64;

// ---------------- K1: transpose x (B,C,N) -> xb (B,N,C) ----------------
__global__ void k_transpose(const float* __restrict__ x, float* __restrict__ xb) {
    __shared__ float tile[64][65];
    int b  = blockIdx.y;
    int n0 = blockIdx.x * 64;
    int tx = threadIdx.x, ty = threadIdx.y;   // 64 x 8
    const float* xp = x + (size_t)b * CCH * NPB;
#pragma unroll
    for (int r = 0; r < 8; ++r) {
        int c = ty + r * 8;
        tile[c][tx] = xp[(size_t)c * NPB + n0 + tx];
    }
    __syncthreads();
    float* xbp = xb + ((size_t)b * NPB + n0) * CCH;
#pragma unroll
    for (int r = 0; r < 8; ++r) {
        int nn = ty + r * 8;
        xbp[(size_t)nn * CCH + tx] = tile[tx][nn];
    }
}

// ---------------- K1b: per-point sum of squares ----------------
__global__ void k_sq(const float* __restrict__ xb, float* __restrict__ sq) {
    int p = blockIdx.x * 256 + threadIdx.x;
    const float4* r = (const float4*)(xb + (size_t)p * CCH);
    float s = 0.0f;
#pragma unroll
    for (int i = 0; i < 16; ++i) {
        float4 v = r[i];
        s += v.x * v.x + v.y * v.y + v.z * v.z + v.w * v.w;
    }
    sq[p] = s;
}

// ---------------- K2: distances + per-(row,colsplit) top-16 ----------------
// 256 threads, (256,1): 256-VGPR budget (empirical: 512-thr blocks cap at
// 128 and cannot prefetch; 256-thr/(256,1) reaches 256 — R7 clean at 116).
// Distance phase software-pipelined: 32 (pair,q)-steps per 16-col subtile,
// 3-stage rotating vf16 buffer pairs, loads issued 2 steps ahead. All
// buffer indices are compile-time (full unroll, s%3). Bitonic selection
// verbatim from R6. key = (monotonic_bits(d) << 32) | col.
__global__ __launch_bounds__(256, 1) void k_knn(const float* __restrict__ xb,
                                                const float* __restrict__ sq,
                                                u64* __restrict__ cand) {
    int tid  = threadIdx.x;
    int row  = blockIdx.y * 256 + tid;          // global point (per-lane)
    int b    = row >> 12;                       // per-lane on purpose
    int split = blockIdx.x;
    const float* xbB = xb + ((size_t)(b) << 12) * CCH;
    const float* sqB = sq + ((size_t)(b) << 12);

    // my row's features -> registers
    float rr[CCH];
    {
        const float4* rp = (const float4*)(xbB + (size_t)(row & 4095) * CCH);
#pragma unroll
        for (int i = 0; i < 16; ++i) {
            float4 v = rp[i];
            rr[4*i] = v.x; rr[4*i+1] = v.y; rr[4*i+2] = v.z; rr[4*i+3] = v.w;
        }
    }

    u64 list[16];
#pragma unroll
    for (int s = 0; s < 16; ++s) list[s] = ~0ULL;

    int colBase = split * (NPB / SPLITS);       // 512 cols per split
    for (int t = 0; t < (NPB / SPLITS) / 16; ++t) {   // 32 subtiles of 16 cols
        int c0 = colBase + t * 16;
        u64 key[16];
        vf16 bf0[3], bf1[3];
        // step s = pair*4 + q; pair p -> cols (c0+2p, c0+2p+1); addr + q*16
        // prologue: load steps 0,1
#pragma unroll
        for (int s = 0; s < 2; ++s) {
            int p = s >> 2, q = s & 3;
            bf0[s % 3] = *(const vf16*)(xbB + (size_t)(c0 + 2*p) * CCH + q * 16);
            bf1[s % 3] = *(const vf16*)(xbB + (size_t)(c0 + 2*p + 1) * CCH + q * 16);
        }
        float a0 = 0.f, a1 = 0.f;
#pragma unroll
        for (int s = 0; s < 32; ++s) {
            int p = s >> 2, q = s & 3;
            if (q == 0) { a0 = 0.f; a1 = 0.f; }
            if (s + 2 < 32) {                   // depth-2 prefetch
                int sp = s + 2, pp = sp >> 2, qp = sp & 3;
                bf0[sp % 3] = *(const vf16*)(xbB + (size_t)(c0 + 2*pp) * CCH + qp * 16);
                bf1[sp % 3] = *(const vf16*)(xbB + (size_t)(c0 + 2*pp + 1) * CCH + qp * 16);
            }
#pragma unroll
            for (int e = 0; e < 16; ++e) {
                a0 = fmaf(bf0[s % 3][e], rr[q * 16 + e], a0);
                a1 = fmaf(bf1[s % 3][e], rr[q * 16 + e], a1);
            }
            if (q == 3) {
                float d0 = fmaf(-2.f, a0, sqB[c0 + 2*p]);
                float d1 = fmaf(-2.f, a1, sqB[c0 + 2*p + 1]);
                unsigned int f0 = __float_as_uint(d0);
                unsigned int f1 = __float_as_uint(d1);
                f0 ^= (f0 >> 31) ? 0xFFFFFFFFu : 0x80000000u;   // monotonic
                f1 ^= (f1 >> 31) ? 0xFFFFFFFFu : 0x80000000u;
                key[2*p]     = ((u64)f0 << 32) | (unsigned int)(c0 + 2*p);
                key[2*p + 1] = ((u64)f1 << 32) | (unsigned int)(c0 + 2*p + 1);
            }
        }
        // ---- bitonic sort16 ascending (static indices, branchless) ----
#pragma unroll
        for (int kk = 2; kk <= 16; kk <<= 1) {
#pragma unroll
            for (int j = kk >> 1; j > 0; j >>= 1) {
#pragma unroll
                for (int i = 0; i < 16; ++i) {
                    int l = i ^ j;
                    if (l > i) {
                        bool up = ((i & kk) == 0);
                        u64 a = key[i], c = key[l];
                        bool cond = up ? (c < a) : (a < c);
                        key[i] = cond ? c : a;
                        key[l] = cond ? a : c;
                    }
                }
            }
        }
        // ---- merge: keep 16 smallest of (list[16] asc, key[16] asc) ----
        u64 m[16];
#pragma unroll
        for (int i = 0; i < 16; ++i) {
            u64 a = list[i], c = key[15 - i];
            m[i] = (c < a) ? c : a;            // bitonic result
        }
#pragma unroll
        for (int j = 8; j > 0; j >>= 1) {
#pragma unroll
            for (int i = 0; i < 16; ++i) {
                if ((i & j) == 0) {
                    u64 a = m[i], c = m[i + j];
                    bool cond = c < a;
                    m[i]     = cond ? c : a;
                    m[i + j] = cond ? a : c;
                }
            }
        }
#pragma unroll
        for (int i = 0; i < 16; ++i) list[i] = m[i];
    }
    u64* cp = cand + (((size_t)row * SPLITS) + split) * 16;
#pragma unroll
    for (int s = 0; s < 16; ++s) cp[s] = list[s];
}

// ---------------- K3: merge SPLITS sorted 16-lists -> final idx[16] ----------------
__global__ void k_merge(const u64* __restrict__ cand,
                        int* __restrict__ idxo) {
    int row = blockIdx.x * 256 + threadIdx.x;
    const u64* cp = cand + (size_t)row * (SPLITS * 16);
    int p[SPLITS];
#pragma unroll
    for (int s = 0; s < SPLITS; ++s) p[s] = 0;
    for (int k = 0; k < 16; ++k) {
        u64 m = ~0ULL; int w = 0;
#pragma unroll
        for (int s = 0; s < SPLITS; ++s) {
            u64 v = cp[s * 16 + p[s]];
            if (v < m) { m = v; w = s; }       // strict: earlier split wins ties
        }
#pragma unroll
        for (int s = 0; s < SPLITS; ++s) p[s] += (s == w) ? 1 : 0;
        idxo[(size_t)row * 16 + k] = (int)(m & 0xFFFFFFFFu);
    }
}

// ---------------- K4: fused edge-MLP + max over K ----------------
// (256,1): cap 256 VGPR — wa/wb/w2r (192 regs) finally register-resident
// (was capped at 128 since R1 -> weight arrays spilled to scratch).
// h/pre chains split lo/hi for dep-latency; xj loads can batch when unrolled.
__global__ __launch_bounds__(256, 1) void k_mlp(const float* __restrict__ xb,
                                                const int* __restrict__ idx,
                                                const float* __restrict__ W1,
                                                const float* __restrict__ b1,
                                                const float* __restrict__ W2,
                                                const float* __restrict__ b2,
                                                float* __restrict__ out) {
    int lane = threadIdx.x & 63;
    int wave = (blockIdx.x * 256 + threadIdx.x) >> 6;   // 0..2047
    int o = lane;
    float wa[64], wb[64], w2r[64];
#pragma unroll
    for (int c = 0; c < 64; ++c) {
        float w1a = W1[c * 64 + o];
        float w1b = W1[(64 + c) * 64 + o];
        wa[c] = w1a - w1b;
        wb[c] = w1b;
        w2r[c] = W2[c * 64 + o];
    }
    float bb1 = b1[o], bb2 = b2[o];
    int p0 = wave * 16;
    for (int pi = 0; pi < 16; ++pi) {
        int p = p0 + pi;
        int b = p >> 12;
        int n = p & 4095;
        const float* xbB = xb + ((size_t)b << 12) * CCH;
        const float* xi = xbB + (size_t)n * CCH;
        float pl = bb1, ph = 0.f;
#pragma unroll
        for (int c4 = 0; c4 < 8; ++c4) {
            float4 v = *(const float4*)(xi + c4 * 4);
            float4 w = *(const float4*)(xi + 32 + c4 * 4);
            pl = fmaf(v.x, wa[c4 * 4 + 0], pl);
            pl = fmaf(v.y, wa[c4 * 4 + 1], pl);
            pl = fmaf(v.z, wa[c4 * 4 + 2], pl);
            pl = fmaf(v.w, wa[c4 * 4 + 3], pl);
            ph = fmaf(w.x, wa[32 + c4 * 4 + 0], ph);
            ph = fmaf(w.y, wa[32 + c4 * 4 + 1], ph);
            ph = fmaf(w.z, wa[32 + c4 * 4 + 2], ph);
            ph = fmaf(w.w, wa[32 + c4 * 4 + 3], ph);
        }
        float pre = pl + ph;
        const int* ip = idx + (size_t)p * 16;
        float mx = 0.f;
        for (int k = 0; k < 16; ++k) {
            int j = ip[k];
            const float* xj = xbB + (size_t)j * CCH;
            float hl = 0.f, hh = 0.f;
#pragma unroll
            for (int c4 = 0; c4 < 8; ++c4) {
                float4 v = *(const float4*)(xj + c4 * 4);
                float4 w = *(const float4*)(xj + 32 + c4 * 4);
                hl = fmaf(v.x, wb[c4 * 4 + 0], hl);
                hl = fmaf(v.y, wb[c4 * 4 + 1], hl);
                hl = fmaf(v.z, wb[c4 * 4 + 2], hl);
                hl = fmaf(v.w, wb[c4 * 4 + 3], hl);
                hh = fmaf(w.x, wb[32 + c4 * 4 + 0], hh);
                hh = fmaf(w.y, wb[32 + c4 * 4 + 1], hh);
                hh = fmaf(w.z, wb[32 + c4 * 4 + 2], hh);
                hh = fmaf(w.w, wb[32 + c4 * 4 + 3], hh);
            }
            float h1 = fmaxf(pre + hl + hh, 0.f);
            float a0 = bb2, a1 = 0.f, a2 = 0.f, a3 = 0.f;
#pragma unroll
            for (int j4 = 0; j4 < 16; ++j4) {
                float h0  = __int_as_float(__builtin_amdgcn_readlane(__float_as_int(h1), 4*j4+0));
                float hh1 = __int_as_float(__builtin_amdgcn_readlane(__float_as_int(h1), 4*j4+1));
                float h2  = __int_as_float(__builtin_amdgcn_readlane(__float_as_int(h1), 4*j4+2));
                float h3  = __int_as_float(__builtin_amdgcn_readlane(__float_as_int(h1), 4*j4+3));
                a0 = fmaf(h0,  w2r[4*j4+0], a0);
                a1 = fmaf(hh1, w2r[4*j4+1], a1);
                a2 = fmaf(h2,  w2r[4*j4+2], a2);
                a3 = fmaf(h3,  w2r[4*j4+3], a3);
            }
            float acc = (a0 + a1) + (a2 + a3);
            float h2o = fmaxf(acc, 0.f);
            mx = fmaxf(mx, h2o);
        }
        out[((size_t)b * 64 + o) * NPB + n] = mx;
    }
}

extern "C" void kernel_launch(void* const* d_in, const int* in_sizes, int n_in,
                              void* d_out, int out_size, void* d_ws, size_t ws_size,
                              hipStream_t stream) {
    const float* x  = (const float*)d_in[0];
    const float* W1 = (const float*)d_in[1];
    const float* b1 = (const float*)d_in[2];
    const float* W2 = (const float*)d_in[3];
    const float* b2 = (const float*)d_in[4];
    float* out = (float*)d_out;

    char* ws = (char*)d_ws;
    float* xb = (float*)ws;                                       // 8 MB
    float* sq = (float*)(ws + (size_t)8 * 1024 * 1024);           // 128 KB
    u64* cand = (u64*)(ws + (size_t)9 * 1024 * 1024);             // 32 MB
    int* idxb = (int*)(ws + (size_t)9 * 1024 * 1024
                          + (size_t)NPTS * SPLITS * 16 * 8);      // 2 MB

    hipLaunchKernelGGL(k_transpose, dim3(NPB / 64, BB), dim3(64, 8), 0, stream, x, xb);
    hipLaunchKernelGGL(k_sq, dim3(NPTS / 256), dim3(256), 0, stream, xb, sq);
    hipLaunchKernelGGL(k_knn, dim3(SPLITS, NPTS / 256), dim3(256), 0, stream, xb, sq, cand);
    hipLaunchKernelGGL(k_merge, dim3(NPTS / 256), dim3(256), 0, stream, cand, idxb);
    hipLaunchKernelGGL(k_mlp, dim3(512), dim3(256), 0, stream, xb, idxb, W1, b1, W2, b2, out);
}

// Round 10
// 911.423 us; speedup vs baseline: 4.4675x; 1.6311x over previous
//
#include <hip/hip_runtime.h>
#include <stdint.h>

#define BB 8
#define CCH 64
#define NPB 4096
#define KK 16
#define NPTS (BB*NPB)   // 32768
#define SPLITS 8

typedef float vf16 __attribute__((ext_vector_type(16)));
typedef unsigned long long u64;

// ---------------- K1: transpose x (B,C,N) -> xb (B,N,C) ----------------
__global__ void k_transpose(const float* __restrict__ x, float* __restrict__ xb) {
    __shared__ float tile[64][65];
    int b  = blockIdx.y;
    int n0 = blockIdx.x * 64;
    int tx = threadIdx.x, ty = threadIdx.y;   // 64 x 8
    const float* xp = x + (size_t)b * CCH * NPB;
#pragma unroll
    for (int r = 0; r < 8; ++r) {
        int c = ty + r * 8;
        tile[c][tx] = xp[(size_t)c * NPB + n0 + tx];
    }
    __syncthreads();
    float* xbp = xb + ((size_t)b * NPB + n0) * CCH;
#pragma unroll
    for (int r = 0; r < 8; ++r) {
        int nn = ty + r * 8;
        xbp[(size_t)nn * CCH + tx] = tile[tx][nn];
    }
}

// ---------------- K1b: per-point sum of squares ----------------
__global__ void k_sq(const float* __restrict__ xb, float* __restrict__ sq) {
    int p = blockIdx.x * 256 + threadIdx.x;
    const float4* r = (const float4*)(xb + (size_t)p * CCH);
    float s = 0.0f;
#pragma unroll
    for (int i = 0; i < 16; ++i) {
        float4 v = r[i];
        s += v.x * v.x + v.y * v.y + v.z * v.z + v.w * v.w;
    }
    sq[p] = s;
}

// ---------------- K2: distances + per-(row,colsplit) top-16 ----------------
// R6 geometry + body (512 thr, (512,2), bitonic sort/merge, FMA order
// bit-identical) with ONE change: the batch index bu = blockIdx.y>>3 is
// block-uniform BY CONSTRUCTION, so all column/sq addresses are scalar
// (SGPR base + uniform offsets) -> compiler emits s_load for column data
// (R2 evidence: SGPR=112) and v_fma v,s,v consumes it from the scalar RF.
// Row features rr stay per-lane VMEM. Frees the VGPR staging that was
// capping load pipelining at the 128-reg wall.
// key = (monotonic_bits(sq[col] - 2*dot) << 32) | col -> lex (d asc, idx asc)
__global__ __launch_bounds__(512, 2) void k_knn(const float* __restrict__ xb,
                                                const float* __restrict__ sq,
                                                u64* __restrict__ cand) {
    int tid  = threadIdx.x;
    int bu   = blockIdx.y >> 3;                 // block-uniform batch (8 blocks/batch)
    int rloc = ((blockIdx.y & 7) << 9) | tid;   // row within batch (per-lane)
    int row  = (bu << 12) | rloc;
    int split = blockIdx.x;
    const float* xbB = xb + ((size_t)bu << 12) * CCH;   // scalar base
    const float* sqB = sq + ((size_t)bu << 12);

    // my row's features -> registers (per-lane)
    float rr[CCH];
    {
        const float4* rp = (const float4*)(xbB + (size_t)rloc * CCH);
#pragma unroll
        for (int i = 0; i < 16; ++i) {
            float4 v = rp[i];
            rr[4*i] = v.x; rr[4*i+1] = v.y; rr[4*i+2] = v.z; rr[4*i+3] = v.w;
        }
    }

    u64 list[16];
#pragma unroll
    for (int s = 0; s < 16; ++s) list[s] = ~0ULL;

    int colBase = split * (NPB / SPLITS);       // 512 cols per split (uniform)
    for (int t = 0; t < (NPB / SPLITS) / 16; ++t) {   // 32 subtiles of 16 cols
        int c0 = colBase + t * 16;              // uniform
        u64 key[16];
        // ---- distances: EXACT R6 FMA order (bit-identical d) ----
#pragma unroll
        for (int cc = 0; cc < 16; cc += 2) {
            float a0 = 0.f, a1 = 0.f;
            const float* col0 = xbB + (size_t)(c0 + cc) * CCH;       // uniform
            const float* col1 = xbB + (size_t)(c0 + cc + 1) * CCH;   // uniform
#pragma unroll
            for (int q = 0; q < 4; ++q) {
                vf16 v0 = *(const vf16*)(col0 + q * 16);
                vf16 v1 = *(const vf16*)(col1 + q * 16);
#pragma unroll
                for (int e = 0; e < 16; ++e) {
                    a0 = fmaf(v0[e], rr[q * 16 + e], a0);
                    a1 = fmaf(v1[e], rr[q * 16 + e], a1);
                }
            }
            float d0 = fmaf(-2.f, a0, sqB[c0 + cc]);
            float d1 = fmaf(-2.f, a1, sqB[c0 + cc + 1]);
            unsigned int f0 = __float_as_uint(d0);
            unsigned int f1 = __float_as_uint(d1);
            f0 ^= (f0 >> 31) ? 0xFFFFFFFFu : 0x80000000u;   // monotonic
            f1 ^= (f1 >> 31) ? 0xFFFFFFFFu : 0x80000000u;
            key[cc]     = ((u64)f0 << 32) | (unsigned int)(c0 + cc);
            key[cc + 1] = ((u64)f1 << 32) | (unsigned int)(c0 + cc + 1);
        }
        // ---- bitonic sort16 ascending (static indices, branchless) ----
#pragma unroll
        for (int kk = 2; kk <= 16; kk <<= 1) {
#pragma unroll
            for (int j = kk >> 1; j > 0; j >>= 1) {
#pragma unroll
                for (int i = 0; i < 16; ++i) {
                    int l = i ^ j;
                    if (l > i) {
                        bool up = ((i & kk) == 0);
                        u64 a = key[i], c = key[l];
                        bool cond = up ? (c < a) : (a < c);
                        key[i] = cond ? c : a;
                        key[l] = cond ? a : c;
                    }
                }
            }
        }
        // ---- merge: keep 16 smallest of (list[16] asc, key[16] asc) ----
        u64 m[16];
#pragma unroll
        for (int i = 0; i < 16; ++i) {
            u64 a = list[i], c = key[15 - i];
            m[i] = (c < a) ? c : a;            // bitonic result
        }
#pragma unroll
        for (int j = 8; j > 0; j >>= 1) {
#pragma unroll
            for (int i = 0; i < 16; ++i) {
                if ((i & j) == 0) {
                    u64 a = m[i], c = m[i + j];
                    bool cond = c < a;
                    m[i]     = cond ? c : a;
                    m[i + j] = cond ? a : c;
                }
            }
        }
#pragma unroll
        for (int i = 0; i < 16; ++i) list[i] = m[i];
    }
    u64* cp = cand + (((size_t)row * SPLITS) + split) * 16;
#pragma unroll
    for (int s = 0; s < 16; ++s) cp[s] = list[s];
}

// ---------------- K3: merge SPLITS sorted 16-lists -> final idx[16] ----------------
__global__ void k_merge(const u64* __restrict__ cand,
                        int* __restrict__ idxo) {
    int row = blockIdx.x * 256 + threadIdx.x;
    const u64* cp = cand + (size_t)row * (SPLITS * 16);
    int p[SPLITS];
#pragma unroll
    for (int s = 0; s < SPLITS; ++s) p[s] = 0;
    for (int k = 0; k < 16; ++k) {
        u64 m = ~0ULL; int w = 0;
#pragma unroll
        for (int s = 0; s < SPLITS; ++s) {
            u64 v = cp[s * 16 + p[s]];
            if (v < m) { m = v; w = s; }       // strict: earlier split wins ties
        }
#pragma unroll
        for (int s = 0; s < SPLITS; ++s) p[s] += (s == w) ? 1 : 0;
        idxo[(size_t)row * 16 + k] = (int)(m & 0xFFFFFFFFu);
    }
}

// ---------------- K4: fused edge-MLP + max over K (R9 body: (256,1), no spills) ----------------
__global__ __launch_bounds__(256, 1) void k_mlp(const float* __restrict__ xb,
                                                const int* __restrict__ idx,
                                                const float* __restrict__ W1,
                                                const float* __restrict__ b1,
                                                const float* __restrict__ W2,
                                                const float* __restrict__ b2,
                                                float* __restrict__ out) {
    int lane = threadIdx.x & 63;
    int wave = (blockIdx.x * 256 + threadIdx.x) >> 6;   // 0..2047
    int o = lane;
    float wa[64], wb[64], w2r[64];
#pragma unroll
    for (int c = 0; c < 64; ++c) {
        float w1a = W1[c * 64 + o];
        float w1b = W1[(64 + c) * 64 + o];
        wa[c] = w1a - w1b;
        wb[c] = w1b;
        w2r[c] = W2[c * 64 + o];
    }
    float bb1 = b1[o], bb2 = b2[o];
    int p0 = wave * 16;
    for (int pi = 0; pi < 16; ++pi) {
        int p = p0 + pi;
        int b = p >> 12;
        int n = p & 4095;
        const float* xbB = xb + ((size_t)b << 12) * CCH;
        const float* xi = xbB + (size_t)n * CCH;
        float pl = bb1, ph = 0.f;
#pragma unroll
        for (int c4 = 0; c4 < 8; ++c4) {
            float4 v = *(const float4*)(xi + c4 * 4);
            float4 w = *(const float4*)(xi + 32 + c4 * 4);
            pl = fmaf(v.x, wa[c4 * 4 + 0], pl);
            pl = fmaf(v.y, wa[c4 * 4 + 1], pl);
            pl = fmaf(v.z, wa[c4 * 4 + 2], pl);
            pl = fmaf(v.w, wa[c4 * 4 + 3], pl);
            ph = fmaf(w.x, wa[32 + c4 * 4 + 0], ph);
            ph = fmaf(w.y, wa[32 + c4 * 4 + 1], ph);
            ph = fmaf(w.z, wa[32 + c4 * 4 + 2], ph);
            ph = fmaf(w.w, wa[32 + c4 * 4 + 3], ph);
        }
        float pre = pl + ph;
        const int* ip = idx + (size_t)p * 16;
        float mx = 0.f;
        for (int k = 0; k < 16; ++k) {
            int j = ip[k];
            const float* xj = xbB + (size_t)j * CCH;
            float hl = 0.f, hh = 0.f;
#pragma unroll
            for (int c4 = 0; c4 < 8; ++c4) {
                float4 v = *(const float4*)(xj + c4 * 4);
                float4 w = *(const float4*)(xj + 32 + c4 * 4);
                hl = fmaf(v.x, wb[c4 * 4 + 0], hl);
                hl = fmaf(v.y, wb[c4 * 4 + 1], hl);
                hl = fmaf(v.z, wb[c4 * 4 + 2], hl);
                hl = fmaf(v.w, wb[c4 * 4 + 3], hl);
                hh = fmaf(w.x, wb[32 + c4 * 4 + 0], hh);
                hh = fmaf(w.y, wb[32 + c4 * 4 + 1], hh);
                hh = fmaf(w.z, wb[32 + c4 * 4 + 2], hh);
                hh = fmaf(w.w, wb[32 + c4 * 4 + 3], hh);
            }
            float h1 = fmaxf(pre + hl + hh, 0.f);
            float a0 = bb2, a1 = 0.f, a2 = 0.f, a3 = 0.f;
#pragma unroll
            for (int j4 = 0; j4 < 16; ++j4) {
                float h0  = __int_as_float(__builtin_amdgcn_readlane(__float_as_int(h1), 4*j4+0));
                float hh1 = __int_as_float(__builtin_amdgcn_readlane(__float_as_int(h1), 4*j4+1));
                float h2  = __int_as_float(__builtin_amdgcn_readlane(__float_as_int(h1), 4*j4+2));
                float h3  = __int_as_float(__builtin_amdgcn_readlane(__float_as_int(h1), 4*j4+3));
                a0 = fmaf(h0,  w2r[4*j4+0], a0);
                a1 = fmaf(hh1, w2r[4*j4+1], a1);
                a2 = fmaf(h2,  w2r[4*j4+2], a2);
                a3 = fmaf(h3,  w2r[4*j4+3], a3);
            }
            float acc = (a0 + a1) + (a2 + a3);
            float h2o = fmaxf(acc, 0.f);
            mx = fmaxf(mx, h2o);
        }
        out[((size_t)b * 64 + o) * NPB + n] = mx;
    }
}

extern "C" void kernel_launch(void* const* d_in, const int* in_sizes, int n_in,
                              void* d_out, int out_size, void* d_ws, size_t ws_size,
                              hipStream_t stream) {
    const float* x  = (const float*)d_in[0];
    const float* W1 = (const float*)d_in[1];
    const float* b1 = (const float*)d_in[2];
    const float* W2 = (const float*)d_in[3];
    const float* b2 = (const float*)d_in[4];
    float* out = (float*)d_out;

    char* ws = (char*)d_ws;
    float* xb = (float*)ws;                                       // 8 MB
    float* sq = (float*)(ws + (size_t)8 * 1024 * 1024);           // 128 KB
    u64* cand = (u64*)(ws + (size_t)9 * 1024 * 1024);             // 32 MB
    int* idxb = (int*)(ws + (size_t)9 * 1024 * 1024
                          + (size_t)NPTS * SPLITS * 16 * 8);      // 2 MB

    hipLaunchKernelGGL(k_transpose, dim3(NPB / 64, BB), dim3(64, 8), 0, stream, x, xb);
    hipLaunchKernelGGL(k_sq, dim3(NPTS / 256), dim3(256), 0, stream, xb, sq);
    hipLaunchKernelGGL(k_knn, dim3(SPLITS, NPTS / 512), dim3(512), 0, stream, xb, sq, cand);
    hipLaunchKernelGGL(k_merge, dim3(NPTS / 256), dim3(256), 0, stream, cand, idxb);
    hipLaunchKernelGGL(k_mlp, dim3(512), dim3(256), 0, stream, xb, idxb, W1, b1, W2, b2, out);
}

// Round 11
// 806.285 us; speedup vs baseline: 5.0501x; 1.1304x over previous
//
#include <hip/hip_runtime.h>
#include <stdint.h>

#define BB 8
#define CCH 64
#define NPB 4096
#define KK 16
#define NPTS (BB*NPB)   // 32768
#define SPLITS 8

typedef float vf16 __attribute__((ext_vector_type(16)));
typedef unsigned long long u64;

// ---------------- K1: transpose x (B,C,N) -> xb (B,N,C) ----------------
__global__ void k_transpose(const float* __restrict__ x, float* __restrict__ xb) {
    __shared__ float tile[64][65];
    int b  = blockIdx.y;
    int n0 = blockIdx.x * 64;
    int tx = threadIdx.x, ty = threadIdx.y;   // 64 x 8
    const float* xp = x + (size_t)b * CCH * NPB;
#pragma unroll
    for (int r = 0; r < 8; ++r) {
        int c = ty + r * 8;
        tile[c][tx] = xp[(size_t)c * NPB + n0 + tx];
    }
    __syncthreads();
    float* xbp = xb + ((size_t)b * NPB + n0) * CCH;
#pragma unroll
    for (int r = 0; r < 8; ++r) {
        int nn = ty + r * 8;
        xbp[(size_t)nn * CCH + tx] = tile[tx][nn];
    }
}

// ---------------- K1b: per-point sum of squares ----------------
__global__ void k_sq(const float* __restrict__ xb, float* __restrict__ sq) {
    int p = blockIdx.x * 256 + threadIdx.x;
    const float4* r = (const float4*)(xb + (size_t)p * CCH);
    float s = 0.0f;
#pragma unroll
    for (int i = 0; i < 16; ++i) {
        float4 v = r[i];
        s += v.x * v.x + v.y * v.y + v.z * v.z + v.w * v.w;
    }
    sq[p] = s;
}

// ---------------- K2: distances + per-(row,colsplit) top-16 ----------------
// R10 structure (512 thr, (512,2), block-uniform batch base -> s_load column
// data, SGPR=112 proven) + NEW: cheap u32 min-guard skips the u64 bitonic
// sort+merge for subtiles that provably cannot insert (min_fb > hi32 of
// list[15]); conservative at equality -> selection bit-identical.
// key = (monotonic_bits(sq[col] - 2*dot) << 32) | col -> lex (d asc, idx asc)
__global__ __launch_bounds__(512, 2) void k_knn(const float* __restrict__ xb,
                                                const float* __restrict__ sq,
                                                u64* __restrict__ cand) {
    int tid  = threadIdx.x;
    int bu   = blockIdx.y >> 3;                 // block-uniform batch (8 blocks/batch)
    int rloc = ((blockIdx.y & 7) << 9) | tid;   // row within batch (per-lane)
    int row  = (bu << 12) | rloc;
    int split = blockIdx.x;
    const float* xbB = xb + ((size_t)bu << 12) * CCH;   // scalar base
    const float* sqB = sq + ((size_t)bu << 12);

    // my row's features -> registers (per-lane)
    float rr[CCH];
    {
        const float4* rp = (const float4*)(xbB + (size_t)rloc * CCH);
#pragma unroll
        for (int i = 0; i < 16; ++i) {
            float4 v = rp[i];
            rr[4*i] = v.x; rr[4*i+1] = v.y; rr[4*i+2] = v.z; rr[4*i+3] = v.w;
        }
    }

    u64 list[16];
#pragma unroll
    for (int s = 0; s < 16; ++s) list[s] = ~0ULL;

    int colBase = split * (NPB / SPLITS);       // 512 cols per split (uniform)
    for (int t = 0; t < (NPB / SPLITS) / 16; ++t) {   // 32 subtiles of 16 cols
        int c0 = colBase + t * 16;              // uniform
        unsigned int fb[16];
        // ---- distances: EXACT R10 FMA order (bit-identical d) ----
#pragma unroll
        for (int cc = 0; cc < 16; cc += 2) {
            float a0 = 0.f, a1 = 0.f;
            const float* col0 = xbB + (size_t)(c0 + cc) * CCH;       // uniform
            const float* col1 = xbB + (size_t)(c0 + cc + 1) * CCH;   // uniform
#pragma unroll
            for (int q = 0; q < 4; ++q) {
                vf16 v0 = *(const vf16*)(col0 + q * 16);
                vf16 v1 = *(const vf16*)(col1 + q * 16);
#pragma unroll
                for (int e = 0; e < 16; ++e) {
                    a0 = fmaf(v0[e], rr[q * 16 + e], a0);
                    a1 = fmaf(v1[e], rr[q * 16 + e], a1);
                }
            }
            float d0 = fmaf(-2.f, a0, sqB[c0 + cc]);
            float d1 = fmaf(-2.f, a1, sqB[c0 + cc + 1]);
            unsigned int f0 = __float_as_uint(d0);
            unsigned int f1 = __float_as_uint(d1);
            f0 ^= (f0 >> 31) ? 0xFFFFFFFFu : 0x80000000u;   // monotonic
            f1 ^= (f1 >> 31) ? 0xFFFFFFFFu : 0x80000000u;
            fb[cc]     = f0;
            fb[cc + 1] = f1;
        }
        // ---- guard: can this subtile possibly insert? (u32 min tree) ----
        unsigned int mn = fb[0];
#pragma unroll
        for (int i = 1; i < 16; ++i) mn = (fb[i] < mn) ? fb[i] : mn;
        bool maybe = mn <= (unsigned int)(list[15] >> 32);
        if (__any(maybe)) {
            u64 key[16];
#pragma unroll
            for (int i = 0; i < 16; ++i)
                key[i] = ((u64)fb[i] << 32) | (unsigned int)(c0 + i);
            // ---- bitonic sort16 ascending (static indices, branchless) ----
#pragma unroll
            for (int kk = 2; kk <= 16; kk <<= 1) {
#pragma unroll
                for (int j = kk >> 1; j > 0; j >>= 1) {
#pragma unroll
                    for (int i = 0; i < 16; ++i) {
                        int l = i ^ j;
                        if (l > i) {
                            bool up = ((i & kk) == 0);
                            u64 a = key[i], c = key[l];
                            bool cond = up ? (c < a) : (a < c);
                            key[i] = cond ? c : a;
                            key[l] = cond ? a : c;
                        }
                    }
                }
            }
            // ---- merge: keep 16 smallest of (list asc, key asc) ----
            u64 m[16];
#pragma unroll
            for (int i = 0; i < 16; ++i) {
                u64 a = list[i], c = key[15 - i];
                m[i] = (c < a) ? c : a;            // bitonic result
            }
#pragma unroll
            for (int j = 8; j > 0; j >>= 1) {
#pragma unroll
                for (int i = 0; i < 16; ++i) {
                    if ((i & j) == 0) {
                        u64 a = m[i], c = m[i + j];
                        bool cond = c < a;
                        m[i]     = cond ? c : a;
                        m[i + j] = cond ? a : c;
                    }
                }
            }
#pragma unroll
            for (int i = 0; i < 16; ++i) list[i] = m[i];
        }
    }
    u64* cp = cand + (((size_t)row * SPLITS) + split) * 16;
#pragma unroll
    for (int s = 0; s < 16; ++s) cp[s] = list[s];
}

// ---------------- K3: merge SPLITS sorted 16-lists -> final idx[16] ----------------
__global__ void k_merge(const u64* __restrict__ cand,
                        int* __restrict__ idxo) {
    int row = blockIdx.x * 256 + threadIdx.x;
    const u64* cp = cand + (size_t)row * (SPLITS * 16);
    int p[SPLITS];
#pragma unroll
    for (int s = 0; s < SPLITS; ++s) p[s] = 0;
    for (int k = 0; k < 16; ++k) {
        u64 m = ~0ULL; int w = 0;
#pragma unroll
        for (int s = 0; s < SPLITS; ++s) {
            u64 v = cp[s * 16 + p[s]];
            if (v < m) { m = v; w = s; }       // strict: earlier split wins ties
        }
#pragma unroll
        for (int s = 0; s < SPLITS; ++s) p[s] += (s == w) ? 1 : 0;
        idxo[(size_t)row * 16 + k] = (int)(m & 0xFFFFFFFFu);
    }
}

// ---------------- K4: fused edge-MLP + max over K ----------------
// (256,1) 256-VGPR budget (weights register-resident). NEW: wave id made
// provably scalar via readfirstlane -> p/n/idx/xi/xj all wave-uniform ->
// compiler emits s_load for row data (same mechanism proven in k_knn R10);
// FMAs become v_fma v,s,v, freeing the VMEM path entirely.
__global__ __launch_bounds__(256, 1) void k_mlp(const float* __restrict__ xb,
                                                const int* __restrict__ idx,
                                                const float* __restrict__ W1,
                                                const float* __restrict__ b1,
                                                const float* __restrict__ W2,
                                                const float* __restrict__ b2,
                                                float* __restrict__ out) {
    int lane = threadIdx.x & 63;
    int wib  = __builtin_amdgcn_readfirstlane(threadIdx.x >> 6);  // scalar 0..3
    int wave = blockIdx.x * 4 + wib;                              // scalar 0..2047
    int o = lane;
    float wa[64], wb[64], w2r[64];
#pragma unroll
    for (int c = 0; c < 64; ++c) {
        float w1a = W1[c * 64 + o];
        float w1b = W1[(64 + c) * 64 + o];
        wa[c] = w1a - w1b;
        wb[c] = w1b;
        w2r[c] = W2[c * 64 + o];
    }
    float bb1 = b1[o], bb2 = b2[o];
    int p0 = wave * 16;
    for (int pi = 0; pi < 16; ++pi) {
        int p = p0 + pi;                        // scalar
        int b = p >> 12;
        int n = p & 4095;
        const float* xbB = xb + ((size_t)b << 12) * CCH;    // scalar base
        const float* xi = xbB + (size_t)n * CCH;            // scalar
        float pl = bb1, ph = 0.f;
#pragma unroll
        for (int c4 = 0; c4 < 8; ++c4) {
            float4 v = *(const float4*)(xi + c4 * 4);
            float4 w = *(const float4*)(xi + 32 + c4 * 4);
            pl = fmaf(v.x, wa[c4 * 4 + 0], pl);
            pl = fmaf(v.y, wa[c4 * 4 + 1], pl);
            pl = fmaf(v.z, wa[c4 * 4 + 2], pl);
            pl = fmaf(v.w, wa[c4 * 4 + 3], pl);
            ph = fmaf(w.x, wa[32 + c4 * 4 + 0], ph);
            ph = fmaf(w.y, wa[32 + c4 * 4 + 1], ph);
            ph = fmaf(w.z, wa[32 + c4 * 4 + 2], ph);
            ph = fmaf(w.w, wa[32 + c4 * 4 + 3], ph);
        }
        float pre = pl + ph;
        const int* ip = idx + (size_t)p * 16;   // scalar
        float mx = 0.f;
        for (int k = 0; k < 16; ++k) {
            int j = ip[k];                      // scalar (uniform load)
            const float* xj = xbB + (size_t)j * CCH;        // scalar
            float hl = 0.f, hh = 0.f;
#pragma unroll
            for (int c4 = 0; c4 < 8; ++c4) {
                float4 v = *(const float4*)(xj + c4 * 4);
                float4 w = *(const float4*)(xj + 32 + c4 * 4);
                hl = fmaf(v.x, wb[c4 * 4 + 0], hl);
                hl = fmaf(v.y, wb[c4 * 4 + 1], hl);
                hl = fmaf(v.z, wb[c4 * 4 + 2], hl);
                hl = fmaf(v.w, wb[c4 * 4 + 3], hl);
                hh = fmaf(w.x, wb[32 + c4 * 4 + 0], hh);
                hh = fmaf(w.y, wb[32 + c4 * 4 + 1], hh);
                hh = fmaf(w.z, wb[32 + c4 * 4 + 2], hh);
                hh = fmaf(w.w, wb[32 + c4 * 4 + 3], hh);
            }
            float h1 = fmaxf(pre + hl + hh, 0.f);
            float a0 = bb2, a1 = 0.f, a2 = 0.f, a3 = 0.f;
#pragma unroll
            for (int j4 = 0; j4 < 16; ++j4) {
                float h0  = __int_as_float(__builtin_amdgcn_readlane(__float_as_int(h1), 4*j4+0));
                float hh1 = __int_as_float(__builtin_amdgcn_readlane(__float_as_int(h1), 4*j4+1));
                float h2  = __int_as_float(__builtin_amdgcn_readlane(__float_as_int(h1), 4*j4+2));
                float h3  = __int_as_float(__builtin_amdgcn_readlane(__float_as_int(h1), 4*j4+3));
                a0 = fmaf(h0,  w2r[4*j4+0], a0);
                a1 = fmaf(hh1, w2r[4*j4+1], a1);
                a2 = fmaf(h2,  w2r[4*j4+2], a2);
                a3 = fmaf(h3,  w2r[4*j4+3], a3);
            }
            float acc = (a0 + a1) + (a2 + a3);
            float h2o = fmaxf(acc, 0.f);
            mx = fmaxf(mx, h2o);
        }
        out[((size_t)b * 64 + o) * NPB + n] = mx;
    }
}

extern "C" void kernel_launch(void* const* d_in, const int* in_sizes, int n_in,
                              void* d_out, int out_size, void* d_ws, size_t ws_size,
                              hipStream_t stream) {
    const float* x  = (const float*)d_in[0];
    const float* W1 = (const float*)d_in[1];
    const float* b1 = (const float*)d_in[2];
    const float* W2 = (const float*)d_in[3];
    const float* b2 = (const float*)d_in[4];
    float* out = (float*)d_out;

    char* ws = (char*)d_ws;
    float* xb = (float*)ws;                                       // 8 MB
    float* sq = (float*)(ws + (size_t)8 * 1024 * 1024);           // 128 KB
    u64* cand = (u64*)(ws + (size_t)9 * 1024 * 1024);             // 32 MB
    int* idxb = (int*)(ws + (size_t)9 * 1024 * 1024
                          + (size_t)NPTS * SPLITS * 16 * 8);      // 2 MB

    hipLaunchKernelGGL(k_transpose, dim3(NPB / 64, BB), dim3(64, 8), 0, stream, x, xb);
    hipLaunchKernelGGL(k_sq, dim3(NPTS / 256), dim3(256), 0, stream, xb, sq);
    hipLaunchKernelGGL(k_knn, dim3(SPLITS, NPTS / 512), dim3(512), 0, stream, xb, sq, cand);
    hipLaunchKernelGGL(k_merge, dim3(NPTS / 256), dim3(256), 0, stream, cand, idxb);
    hipLaunchKernelGGL(k_mlp, dim3(512), dim3(256), 0, stream, xb, idxb, W1, b1, W2, b2, out);
}

// Round 12
// 783.393 us; speedup vs baseline: 5.1977x; 1.0292x over previous
//
#include <hip/hip_runtime.h>
#include <stdint.h>

#define BB 8
#define CCH 64
#define NPB 4096
#define KK 16
#define NPTS (BB*NPB)   // 32768
#define SPLITS 8

typedef float f32x2 __attribute__((ext_vector_type(2)));
typedef unsigned long long u64;

// ---------------- K1: transpose x (B,C,N) -> xb (B,N,C) ----------------
__global__ void k_transpose(const float* __restrict__ x, float* __restrict__ xb) {
    __shared__ float tile[64][65];
    int b  = blockIdx.y;
    int n0 = blockIdx.x * 64;
    int tx = threadIdx.x, ty = threadIdx.y;   // 64 x 8
    const float* xp = x + (size_t)b * CCH * NPB;
#pragma unroll
    for (int r = 0; r < 8; ++r) {
        int c = ty + r * 8;
        tile[c][tx] = xp[(size_t)c * NPB + n0 + tx];
    }
    __syncthreads();
    float* xbp = xb + ((size_t)b * NPB + n0) * CCH;
#pragma unroll
    for (int r = 0; r < 8; ++r) {
        int nn = ty + r * 8;
        xbp[(size_t)nn * CCH + tx] = tile[tx][nn];
    }
}

// ---------------- K1b: per-point sum of squares ----------------
__global__ void k_sq(const float* __restrict__ xb, float* __restrict__ sq) {
    int p = blockIdx.x * 256 + threadIdx.x;
    const float4* r = (const float4*)(xb + (size_t)p * CCH);
    float s = 0.0f;
#pragma unroll
    for (int i = 0; i < 16; ++i) {
        float4 v = r[i];
        s += v.x * v.x + v.y * v.y + v.z * v.z + v.w * v.w;
    }
    sq[p] = s;
}

// ---------------- K2: distances + per-(row,colsplit) top-16 ----------------
// R10 structure (512 thr, (512,2), block-uniform batch base -> s_load column
// data) with the distance FMAs rewritten over f32x2 so LLVM emits
// v_pk_fma_f32 (VOP3P packed fp32 = the only path to the 157 TF vector rate;
// scalar v_fma was issuing 2x the instructions). One SGPR-pair operand per
// VOP3P is legal -> scalarized column data feeds packed FMA directly.
// Selection: R6 bitonic sort16+merge16 on u64 keys, verbatim (guard dropped:
// R11 proved __any-gated skips never fire with 64 lanes).
// key = (monotonic_bits(sq[col] - 2*dot) << 32) | col -> lex (d asc, idx asc)
__global__ __launch_bounds__(512, 2) void k_knn(const float* __restrict__ xb,
                                                const float* __restrict__ sq,
                                                u64* __restrict__ cand) {
    int tid  = threadIdx.x;
    int bu   = blockIdx.y >> 3;                 // block-uniform batch (8 blocks/batch)
    int rloc = ((blockIdx.y & 7) << 9) | tid;   // row within batch (per-lane)
    int row  = (bu << 12) | rloc;
    int split = blockIdx.x;
    const float* xbB = xb + ((size_t)bu << 12) * CCH;   // scalar base
    const float* sqB = sq + ((size_t)bu << 12);

    // my row's features -> registers (per-lane, as f32x2 pairs)
    f32x2 rr[32];
    {
        const f32x2* rp = (const f32x2*)(xbB + (size_t)rloc * CCH);
#pragma unroll
        for (int i = 0; i < 32; ++i) rr[i] = rp[i];
    }

    u64 list[16];
#pragma unroll
    for (int s = 0; s < 16; ++s) list[s] = ~0ULL;

    int colBase = split * (NPB / SPLITS);       // 512 cols per split (uniform)
    for (int t = 0; t < (NPB / SPLITS) / 16; ++t) {   // 32 subtiles of 16 cols
        int c0 = colBase + t * 16;              // uniform
        u64 key[16];
#pragma unroll
        for (int cc = 0; cc < 16; cc += 2) {
            f32x2 a0 = {0.f, 0.f}, a1 = {0.f, 0.f};
            const f32x2* col0 = (const f32x2*)(xbB + (size_t)(c0 + cc) * CCH);     // uniform
            const f32x2* col1 = (const f32x2*)(xbB + (size_t)(c0 + cc + 1) * CCH); // uniform
#pragma unroll
            for (int e = 0; e < 32; ++e) {
                a0 += col0[e] * rr[e];          // v_pk_fma_f32 (contract)
                a1 += col1[e] * rr[e];
            }
            float d0 = fmaf(-2.f, a0.x + a0.y, sqB[c0 + cc]);
            float d1 = fmaf(-2.f, a1.x + a1.y, sqB[c0 + cc + 1]);
            unsigned int f0 = __float_as_uint(d0);
            unsigned int f1 = __float_as_uint(d1);
            f0 ^= (f0 >> 31) ? 0xFFFFFFFFu : 0x80000000u;   // monotonic
            f1 ^= (f1 >> 31) ? 0xFFFFFFFFu : 0x80000000u;
            key[cc]     = ((u64)f0 << 32) | (unsigned int)(c0 + cc);
            key[cc + 1] = ((u64)f1 << 32) | (unsigned int)(c0 + cc + 1);
        }
        // ---- bitonic sort16 ascending (static indices, branchless) ----
#pragma unroll
        for (int kk = 2; kk <= 16; kk <<= 1) {
#pragma unroll
            for (int j = kk >> 1; j > 0; j >>= 1) {
#pragma unroll
                for (int i = 0; i < 16; ++i) {
                    int l = i ^ j;
                    if (l > i) {
                        bool up = ((i & kk) == 0);
                        u64 a = key[i], c = key[l];
                        bool cond = up ? (c < a) : (a < c);
                        key[i] = cond ? c : a;
                        key[l] = cond ? a : c;
                    }
                }
            }
        }
        // ---- merge: keep 16 smallest of (list[16] asc, key[16] asc) ----
        u64 m[16];
#pragma unroll
        for (int i = 0; i < 16; ++i) {
            u64 a = list[i], c = key[15 - i];
            m[i] = (c < a) ? c : a;            // bitonic result
        }
#pragma unroll
        for (int j = 8; j > 0; j >>= 1) {
#pragma unroll
            for (int i = 0; i < 16; ++i) {
                if ((i & j) == 0) {
                    u64 a = m[i], c = m[i + j];
                    bool cond = c < a;
                    m[i]     = cond ? c : a;
                    m[i + j] = cond ? a : c;
                }
            }
        }
#pragma unroll
        for (int i = 0; i < 16; ++i) list[i] = m[i];
    }
    u64* cp = cand + (((size_t)row * SPLITS) + split) * 16;
#pragma unroll
    for (int s = 0; s < 16; ++s) cp[s] = list[s];
}

// ---------------- K3: merge SPLITS sorted 16-lists -> final idx[16] ----------------
__global__ void k_merge(const u64* __restrict__ cand,
                        int* __restrict__ idxo) {
    int row = blockIdx.x * 256 + threadIdx.x;
    const u64* cp = cand + (size_t)row * (SPLITS * 16);
    int p[SPLITS];
#pragma unroll
    for (int s = 0; s < SPLITS; ++s) p[s] = 0;
    for (int k = 0; k < 16; ++k) {
        u64 m = ~0ULL; int w = 0;
#pragma unroll
        for (int s = 0; s < SPLITS; ++s) {
            u64 v = cp[s * 16 + p[s]];
            if (v < m) { m = v; w = s; }       // strict: earlier split wins ties
        }
#pragma unroll
        for (int s = 0; s < SPLITS; ++s) p[s] += (s == w) ? 1 : 0;
        idxo[(size_t)row * 16 + k] = (int)(m & 0xFFFFFFFFu);
    }
}

// ---------------- K4: fused edge-MLP + max over K ----------------
// R11 structure ((256,1) 256-VGPR budget, scalar wave id -> s_load row data)
// with layer-1 FMAs packed over f32x2 (v_pk_fma_f32): 128 -> 64 instrs/edge.
// Layer 2 (readlane broadcast chain) is unpackable; 4 independent chains.
__global__ __launch_bounds__(256, 1) void k_mlp(const float* __restrict__ xb,
                                                const int* __restrict__ idx,
                                                const float* __restrict__ W1,
                                                const float* __restrict__ b1,
                                                const float* __restrict__ W2,
                                                const float* __restrict__ b2,
                                                float* __restrict__ out) {
    int lane = threadIdx.x & 63;
    int wib  = __builtin_amdgcn_readfirstlane(threadIdx.x >> 6);  // scalar 0..3
    int wave = blockIdx.x * 4 + wib;                              // scalar 0..2047
    int o = lane;
    f32x2 wa2[32], wb2[32];
    float w2r[64];
#pragma unroll
    for (int c = 0; c < 32; ++c) {
        float w1a0 = W1[(2*c) * 64 + o];
        float w1b0 = W1[(64 + 2*c) * 64 + o];
        float w1a1 = W1[(2*c + 1) * 64 + o];
        float w1b1 = W1[(64 + 2*c + 1) * 64 + o];
        wa2[c] = (f32x2){w1a0 - w1b0, w1a1 - w1b1};
        wb2[c] = (f32x2){w1b0, w1b1};
    }
#pragma unroll
    for (int c = 0; c < 64; ++c) w2r[c] = W2[c * 64 + o];
    float bb1 = b1[o], bb2 = b2[o];
    int p0 = wave * 16;
    for (int pi = 0; pi < 16; ++pi) {
        int p = p0 + pi;                        // scalar
        int b = p >> 12;
        int n = p & 4095;
        const float* xbB = xb + ((size_t)b << 12) * CCH;    // scalar base
        const float* xi = xbB + (size_t)n * CCH;            // scalar
        f32x2 acc1 = {bb1, 0.f};
        const f32x2* xi2 = (const f32x2*)xi;
#pragma unroll
        for (int e = 0; e < 32; ++e) acc1 += xi2[e] * wa2[e];   // v_pk_fma
        float pre = acc1.x + acc1.y;
        const int* ip = idx + (size_t)p * 16;   // scalar
        float mx = 0.f;
        for (int k = 0; k < 16; ++k) {
            int j = ip[k];                      // scalar (uniform load)
            const float* xj = xbB + (size_t)j * CCH;        // scalar
            const f32x2* xj2 = (const f32x2*)xj;
            f32x2 acch = {0.f, 0.f};
#pragma unroll
            for (int e = 0; e < 32; ++e) acch += xj2[e] * wb2[e];   // v_pk_fma
            float h1 = fmaxf(pre + acch.x + acch.y, 0.f);
            float a0 = bb2, a1 = 0.f, a2 = 0.f, a3 = 0.f;
#pragma unroll
            for (int j4 = 0; j4 < 16; ++j4) {
                float h0  = __int_as_float(__builtin_amdgcn_readlane(__float_as_int(h1), 4*j4+0));
                float hh1 = __int_as_float(__builtin_amdgcn_readlane(__float_as_int(h1), 4*j4+1));
                float h2  = __int_as_float(__builtin_amdgcn_readlane(__float_as_int(h1), 4*j4+2));
                float h3  = __int_as_float(__builtin_amdgcn_readlane(__float_as_int(h1), 4*j4+3));
                a0 = fmaf(h0,  w2r[4*j4+0], a0);
                a1 = fmaf(hh1, w2r[4*j4+1], a1);
                a2 = fmaf(h2,  w2r[4*j4+2], a2);
                a3 = fmaf(h3,  w2r[4*j4+3], a3);
            }
            float acc = (a0 + a1) + (a2 + a3);
            float h2o = fmaxf(acc, 0.f);
            mx = fmaxf(mx, h2o);
        }
        out[((size_t)b * 64 + o) * NPB + n] = mx;
    }
}

extern "C" void kernel_launch(void* const* d_in, const int* in_sizes, int n_in,
                              void* d_out, int out_size, void* d_ws, size_t ws_size,
                              hipStream_t stream) {
    const float* x  = (const float*)d_in[0];
    const float* W1 = (const float*)d_in[1];
    const float* b1 = (const float*)d_in[2];
    const float* W2 = (const float*)d_in[3];
    const float* b2 = (const float*)d_in[4];
    float* out = (float*)d_out;

    char* ws = (char*)d_ws;
    float* xb = (float*)ws;                                       // 8 MB
    float* sq = (float*)(ws + (size_t)8 * 1024 * 1024);           // 128 KB
    u64* cand = (u64*)(ws + (size_t)9 * 1024 * 1024);             // 32 MB
    int* idxb = (int*)(ws + (size_t)9 * 1024 * 1024
                          + (size_t)NPTS * SPLITS * 16 * 8);      // 2 MB

    hipLaunchKernelGGL(k_transpose, dim3(NPB / 64, BB), dim3(64, 8), 0, stream, x, xb);
    hipLaunchKernelGGL(k_sq, dim3(NPTS / 256), dim3(256), 0, stream, xb, sq);
    hipLaunchKernelGGL(k_knn, dim3(SPLITS, NPTS / 512), dim3(512), 0, stream, xb, sq, cand);
    hipLaunchKernelGGL(k_merge, dim3(NPTS / 256), dim3(256), 0, stream, cand, idxb);
    hipLaunchKernelGGL(k_mlp, dim3(512), dim3(256), 0, stream, xb, idxb, W1, b1, W2, b2, out);
}

// Round 13
// 775.843 us; speedup vs baseline: 5.2482x; 1.0097x over previous
//
#include <hip/hip_runtime.h>
#include <stdint.h>

#define BB 8
#define CCH 64
#define NPB 4096
#define KK 16
#define NPTS (BB*NPB)   // 32768
#define SPLITS 8

typedef float f32x2 __attribute__((ext_vector_type(2)));
typedef unsigned long long u64;

// ---------------- K1: transpose x (B,C,N) -> xb (B,N,C) ----------------
__global__ void k_transpose(const float* __restrict__ x, float* __restrict__ xb) {
    __shared__ float tile[64][65];
    int b  = blockIdx.y;
    int n0 = blockIdx.x * 64;
    int tx = threadIdx.x, ty = threadIdx.y;   // 64 x 8
    const float* xp = x + (size_t)b * CCH * NPB;
#pragma unroll
    for (int r = 0; r < 8; ++r) {
        int c = ty + r * 8;
        tile[c][tx] = xp[(size_t)c * NPB + n0 + tx];
    }
    __syncthreads();
    float* xbp = xb + ((size_t)b * NPB + n0) * CCH;
#pragma unroll
    for (int r = 0; r < 8; ++r) {
        int nn = ty + r * 8;
        xbp[(size_t)nn * CCH + tx] = tile[tx][nn];
    }
}

// ---------------- K1b: per-point sum of squares ----------------
__global__ void k_sq(const float* __restrict__ xb, float* __restrict__ sq) {
    int p = blockIdx.x * 256 + threadIdx.x;
    const float4* r = (const float4*)(xb + (size_t)p * CCH);
    float s = 0.0f;
#pragma unroll
    for (int i = 0; i < 16; ++i) {
        float4 v = r[i];
        s += v.x * v.x + v.y * v.y + v.z * v.z + v.w * v.w;
    }
    sq[p] = s;
}

// sort16 ascending on u64 keys (bitonic, static indices) — proven since R6
__device__ __forceinline__ void sort16(u64* key) {
#pragma unroll
    for (int kk = 2; kk <= 16; kk <<= 1) {
#pragma unroll
        for (int j = kk >> 1; j > 0; j >>= 1) {
#pragma unroll
            for (int i = 0; i < 16; ++i) {
                int l = i ^ j;
                if (l > i) {
                    bool up = ((i & kk) == 0);
                    u64 a = key[i], c = key[l];
                    bool cond = up ? (c < a) : (a < c);
                    key[i] = cond ? c : a;
                    key[l] = cond ? a : c;
                }
            }
        }
    }
}

// keep 16 smallest of (list asc, key asc) -> list asc — proven since R6
__device__ __forceinline__ void merge16(u64* list, const u64* key) {
    u64 m[16];
#pragma unroll
    for (int i = 0; i < 16; ++i) {
        u64 a = list[i], c = key[15 - i];
        m[i] = (c < a) ? c : a;
    }
#pragma unroll
    for (int j = 8; j > 0; j >>= 1) {
#pragma unroll
        for (int i = 0; i < 16; ++i) {
            if ((i & j) == 0) {
                u64 a = m[i], c = m[i + j];
                bool cond = c < a;
                m[i]     = cond ? c : a;
                m[i + j] = cond ? a : c;
            }
        }
    }
#pragma unroll
    for (int i = 0; i < 16; ++i) list[i] = m[i];
}

// ---------------- K2: distances + per-(row,colsplit) top-16 ----------------
// 256 thr, (256,1): 256-VGPR budget. Block-uniform batch base (bu =
// blockIdx.y>>4) -> column data via s_load (R10 win). NEW: two independent
// half-split streams (listA: cols [0,256), listB: [256,512)) with 4 column
// dot-products interleaved at source level -> the dependency graph itself
// covers s_load latency (R12 evidence: single-stream is latency-bound at
// VALUBusy 54%, SGPR file limits lookahead to ~1 column). Final exact
// bitonic merge of the two half-lists. d values bit-identical to R12.
// key = (monotonic_bits(sq[col] - 2*dot) << 32) | col -> lex (d asc, idx asc)
__global__ __launch_bounds__(256, 1) void k_knn(const float* __restrict__ xb,
                                                const float* __restrict__ sq,
                                                u64* __restrict__ cand) {
    int tid  = threadIdx.x;
    int bu   = blockIdx.y >> 4;                 // block-uniform batch (16 blocks/batch)
    int rloc = ((blockIdx.y & 15) << 8) | tid;  // row within batch (per-lane)
    int row  = (bu << 12) | rloc;
    int split = blockIdx.x;
    const float* xbB = xb + ((size_t)bu << 12) * CCH;   // scalar base
    const float* sqB = sq + ((size_t)bu << 12);

    // my row's features -> registers (per-lane, as f32x2 pairs)
    f32x2 rr[32];
    {
        const f32x2* rp = (const f32x2*)(xbB + (size_t)rloc * CCH);
#pragma unroll
        for (int i = 0; i < 32; ++i) rr[i] = rp[i];
    }

    u64 listA[16], listB[16];
#pragma unroll
    for (int s = 0; s < 16; ++s) { listA[s] = ~0ULL; listB[s] = ~0ULL; }

    int baseA = split * (NPB / SPLITS);         // uniform
    int baseB = baseA + 256;
    for (int t = 0; t < 16; ++t) {              // 16 subtile-pairs of 16 cols
        int c0A = baseA + t * 16;               // uniform
        int c0B = baseB + t * 16;               // uniform
        unsigned int fbA[16], fbB[16];
        // ---- 4 interleaved column dot-products (2 per stream) ----
#pragma unroll
        for (int cc = 0; cc < 16; cc += 2) {
            f32x2 aA0 = {0.f, 0.f}, aA1 = {0.f, 0.f};
            f32x2 aB0 = {0.f, 0.f}, aB1 = {0.f, 0.f};
            const f32x2* colA0 = (const f32x2*)(xbB + (size_t)(c0A + cc) * CCH);
            const f32x2* colA1 = (const f32x2*)(xbB + (size_t)(c0A + cc + 1) * CCH);
            const f32x2* colB0 = (const f32x2*)(xbB + (size_t)(c0B + cc) * CCH);
            const f32x2* colB1 = (const f32x2*)(xbB + (size_t)(c0B + cc + 1) * CCH);
#pragma unroll
            for (int e = 0; e < 32; ++e) {
                aA0 += colA0[e] * rr[e];
                aA1 += colA1[e] * rr[e];
                aB0 += colB0[e] * rr[e];
                aB1 += colB1[e] * rr[e];
            }
            float dA0 = fmaf(-2.f, aA0.x + aA0.y, sqB[c0A + cc]);
            float dA1 = fmaf(-2.f, aA1.x + aA1.y, sqB[c0A + cc + 1]);
            float dB0 = fmaf(-2.f, aB0.x + aB0.y, sqB[c0B + cc]);
            float dB1 = fmaf(-2.f, aB1.x + aB1.y, sqB[c0B + cc + 1]);
            unsigned int fA0 = __float_as_uint(dA0);
            unsigned int fA1 = __float_as_uint(dA1);
            unsigned int fB0 = __float_as_uint(dB0);
            unsigned int fB1 = __float_as_uint(dB1);
            fA0 ^= (fA0 >> 31) ? 0xFFFFFFFFu : 0x80000000u;   // monotonic
            fA1 ^= (fA1 >> 31) ? 0xFFFFFFFFu : 0x80000000u;
            fB0 ^= (fB0 >> 31) ? 0xFFFFFFFFu : 0x80000000u;
            fB1 ^= (fB1 >> 31) ? 0xFFFFFFFFu : 0x80000000u;
            fbA[cc] = fA0; fbA[cc + 1] = fA1;
            fbB[cc] = fB0; fbB[cc + 1] = fB1;
        }
        // ---- stream A: sort + merge ----
        {
            u64 key[16];
#pragma unroll
            for (int i = 0; i < 16; ++i)
                key[i] = ((u64)fbA[i] << 32) | (unsigned int)(c0A + i);
            sort16(key);
            merge16(listA, key);
        }
        // ---- stream B: sort + merge ----
        {
            u64 key[16];
#pragma unroll
            for (int i = 0; i < 16; ++i)
                key[i] = ((u64)fbB[i] << 32) | (unsigned int)(c0B + i);
            sort16(key);
            merge16(listB, key);
        }
    }
    // ---- final: top-16 of (listA ∪ listB), ascending (exact, keys unique) ----
    merge16(listA, listB);
    u64* cp = cand + (((size_t)row * SPLITS) + split) * 16;
#pragma unroll
    for (int s = 0; s < 16; ++s) cp[s] = listA[s];
}

// ---------------- K3: merge SPLITS sorted 16-lists -> final idx[16] ----------------
__global__ void k_merge(const u64* __restrict__ cand,
                        int* __restrict__ idxo) {
    int row = blockIdx.x * 256 + threadIdx.x;
    const u64* cp = cand + (size_t)row * (SPLITS * 16);
    int p[SPLITS];
#pragma unroll
    for (int s = 0; s < SPLITS; ++s) p[s] = 0;
    for (int k = 0; k < 16; ++k) {
        u64 m = ~0ULL; int w = 0;
#pragma unroll
        for (int s = 0; s < SPLITS; ++s) {
            u64 v = cp[s * 16 + p[s]];
            if (v < m) { m = v; w = s; }       // strict: earlier split wins ties
        }
#pragma unroll
        for (int s = 0; s < SPLITS; ++s) p[s] += (s == w) ? 1 : 0;
        idxo[(size_t)row * 16 + k] = (int)(m & 0xFFFFFFFFu);
    }
}

// ---------------- K4: fused edge-MLP + max over K (R12 body, proven) ----------------
__global__ __launch_bounds__(256, 1) void k_mlp(const float* __restrict__ xb,
                                                const int* __restrict__ idx,
                                                const float* __restrict__ W1,
                                                const float* __restrict__ b1,
                                                const float* __restrict__ W2,
                                                const float* __restrict__ b2,
                                                float* __restrict__ out) {
    int lane = threadIdx.x & 63;
    int wib  = __builtin_amdgcn_readfirstlane(threadIdx.x >> 6);  // scalar 0..3
    int wave = blockIdx.x * 4 + wib;                              // scalar 0..2047
    int o = lane;
    f32x2 wa2[32], wb2[32];
    float w2r[64];
#pragma unroll
    for (int c = 0; c < 32; ++c) {
        float w1a0 = W1[(2*c) * 64 + o];
        float w1b0 = W1[(64 + 2*c) * 64 + o];
        float w1a1 = W1[(2*c + 1) * 64 + o];
        float w1b1 = W1[(64 + 2*c + 1) * 64 + o];
        wa2[c] = (f32x2){w1a0 - w1b0, w1a1 - w1b1};
        wb2[c] = (f32x2){w1b0, w1b1};
    }
#pragma unroll
    for (int c = 0; c < 64; ++c) w2r[c] = W2[c * 64 + o];
    float bb1 = b1[o], bb2 = b2[o];
    int p0 = wave * 16;
    for (int pi = 0; pi < 16; ++pi) {
        int p = p0 + pi;                        // scalar
        int b = p >> 12;
        int n = p & 4095;
        const float* xbB = xb + ((size_t)b << 12) * CCH;    // scalar base
        const float* xi = xbB + (size_t)n * CCH;            // scalar
        f32x2 acc1 = {bb1, 0.f};
        const f32x2* xi2 = (const f32x2*)xi;
#pragma unroll
        for (int e = 0; e < 32; ++e) acc1 += xi2[e] * wa2[e];   // v_pk_fma
        float pre = acc1.x + acc1.y;
        const int* ip = idx + (size_t)p * 16;   // scalar
        float mx = 0.f;
        for (int k = 0; k < 16; ++k) {
            int j = ip[k];                      // scalar (uniform load)
            const float* xj = xbB + (size_t)j * CCH;        // scalar
            const f32x2* xj2 = (const f32x2*)xj;
            f32x2 acch = {0.f, 0.f};
#pragma unroll
            for (int e = 0; e < 32; ++e) acch += xj2[e] * wb2[e];   // v_pk_fma
            float h1 = fmaxf(pre + acch.x + acch.y, 0.f);
            float a0 = bb2, a1 = 0.f, a2 = 0.f, a3 = 0.f;
#pragma unroll
            for (int j4 = 0; j4 < 16; ++j4) {
                float h0  = __int_as_float(__builtin_amdgcn_readlane(__float_as_int(h1), 4*j4+0));
                float hh1 = __int_as_float(__builtin_amdgcn_readlane(__float_as_int(h1), 4*j4+1));
                float h2  = __int_as_float(__builtin_amdgcn_readlane(__float_as_int(h1), 4*j4+2));
                float h3  = __int_as_float(__builtin_amdgcn_readlane(__float_as_int(h1), 4*j4+3));
                a0 = fmaf(h0,  w2r[4*j4+0], a0);
                a1 = fmaf(hh1, w2r[4*j4+1], a1);
                a2 = fmaf(h2,  w2r[4*j4+2], a2);
                a3 = fmaf(h3,  w2r[4*j4+3], a3);
            }
            float acc = (a0 + a1) + (a2 + a3);
            float h2o = fmaxf(acc, 0.f);
            mx = fmaxf(mx, h2o);
        }
        out[((size_t)b * 64 + o) * NPB + n] = mx;
    }
}

extern "C" void kernel_launch(void* const* d_in, const int* in_sizes, int n_in,
                              void* d_out, int out_size, void* d_ws, size_t ws_size,
                              hipStream_t stream) {
    const float* x  = (const float*)d_in[0];
    const float* W1 = (const float*)d_in[1];
    const float* b1 = (const float*)d_in[2];
    const float* W2 = (const float*)d_in[3];
    const float* b2 = (const float*)d_in[4];
    float* out = (float*)d_out;

    char* ws = (char*)d_ws;
    float* xb = (float*)ws;                                       // 8 MB
    float* sq = (float*)(ws + (size_t)8 * 1024 * 1024);           // 128 KB
    u64* cand = (u64*)(ws + (size_t)9 * 1024 * 1024);             // 32 MB
    int* idxb = (int*)(ws + (size_t)9 * 1024 * 1024
                          + (size_t)NPTS * SPLITS * 16 * 8);      // 2 MB

    hipLaunchKernelGGL(k_transpose, dim3(NPB / 64, BB), dim3(64, 8), 0, stream, x, xb);
    hipLaunchKernelGGL(k_sq, dim3(NPTS / 256), dim3(256), 0, stream, xb, sq);
    hipLaunchKernelGGL(k_knn, dim3(SPLITS, NPTS / 256), dim3(256), 0, stream, xb, sq, cand);
    hipLaunchKernelGGL(k_merge, dim3(NPTS / 256), dim3(256), 0, stream, cand, idxb);
    hipLaunchKernelGGL(k_mlp, dim3(512), dim3(256), 0, stream, xb, idxb, W1, b1, W2, b2, out);
}